// Round 9
// baseline (816.181 us; speedup 1.0000x reference)
//
#include <hip/hip_runtime.h>
#include <hip/hip_bf16.h>
#include <cstdint>
#include <cstddef>

#define NU   8000
#define NI   10000
#define NTOT 18000
#define G    4096
#define KP2  18176      // slots: users 0..8063, items 8064..18175
#define NSL  284        // 64-slot tiles
#define NSL128 142      // 128-slot tiles
#define KT8  142        // 128-byte k-tiles
#define UT8  63         // user 128-tiles (63*128 = 8064)

typedef __attribute__((ext_vector_type(4))) float f32x4;

__device__ __forceinline__ float bfu(unsigned short u){
  return __uint_as_float(((unsigned)u)<<16);
}
__device__ __forceinline__ unsigned short f2b(float f){
  __hip_bfloat16 h = __float2bfloat16(f);
  return __builtin_bit_cast(unsigned short, h);
}
__device__ __forceinline__ unsigned char f2f8(float v){
  int p = __builtin_amdgcn_cvt_pk_fp8_f32(v, 0.f, 0, false);
  return (unsigned char)(p & 0xff);
}
template<int SEL>
__device__ __forceinline__ float f8tof(unsigned int w){
  return __builtin_amdgcn_cvt_f32_fp8((int)w, SEL);
}
__device__ __forceinline__ void async16(void* lds, const void* g){
  __builtin_amdgcn_global_load_lds((const __attribute__((address_space(1))) unsigned int*)g,
                                   (__attribute__((address_space(3))) unsigned int*)lds, 16, 0, 0);
}
__device__ __forceinline__ int slot2n(int s){
  return (s < 8064) ? (s < 8000 ? s : -1) : (s-64 < NTOT ? s-64 : -1);
}

// ---------------- K1: q/k/v projections, v rows, wsk = Ws @ k ----------------
__global__ __launch_bounds__(256) void k_proj(
    const float* __restrict__ feats,
    const float* uWq, const float* ubq, const float* uWk, const float* ubk,
    const float* uWv, const float* ubv, const float* uWs,
    const float* iWq, const float* ibq, const float* iWk, const float* ibk,
    const float* iWv, const float* ibv, const float* iWs,
    float* __restrict__ q, unsigned short* __restrict__ vrow, float* __restrict__ wsk)
{
  __shared__ unsigned short Wt[6*4096];
  __shared__ float bl[6*64];
  __shared__ float wacc[128];
  const float* mats[6]  = {uWq,uWk,uWv,iWq,iWk,iWv};
  const float* bias6[6] = {ubq,ubk,ubv,ibq,ibk,ibv};
  int t = threadIdx.x;
  for (int m=0;m<6;m++)
    for (int e=t; e<4096; e+=256){
      int dd = e>>6, jj = e&63;
      Wt[m*4096 + jj*64 + dd] = f2b(mats[m][e]);
    }
  for (int e=t; e<384; e+=256) bl[e] = bias6[e>>6][e&63];
  if (t<128) wacc[t]=0.f;
  __syncthreads();
  int wave=t>>6, lane=t&63;
  int gw = blockIdx.x*4+wave, nw = gridDim.x*4;
  float accU=0.f, accI=0.f;
  for (int n=gw; n<NTOT; n+=nw){
    int br = (n>=NU);
    const unsigned short* W = Wt + br*3*4096;
    const float* bb = bl + br*192;
    float x = feats[(size_t)n*64+lane];
    float qd=bb[lane], kd=bb[64+lane], vd=bb[128+lane];
    #pragma unroll 16
    for (int j=0;j<64;j++){
      float xj = __shfl(x, j, 64);
      qd += xj * bfu(W[       j*64+lane]);
      kd += xj * bfu(W[4096 + j*64+lane]);
      vd += xj * bfu(W[8192 + j*64+lane]);
    }
    q[(size_t)n*64+lane] = qd;
    vrow[(size_t)n*64+lane] = f2b(vd);
    float wsn = br ? iWs[n-NU] : uWs[n];
    if (br) accI += wsn*kd; else accU += wsn*kd;
  }
  atomicAdd(&wacc[lane], accU);
  atomicAdd(&wacc[64+lane], accI);
  __syncthreads();
  if (t<128) atomicAdd(&wsk[t], wacc[t]);
}

// ---------------- K2: per-slot r quantized to fp8; rfs = dequant, rbs = byte ----------------
__global__ __launch_bounds__(256) void k_score(const float* __restrict__ q, const float* __restrict__ wsk,
    const float* ubs, const float* ibs, float* __restrict__ rfs, unsigned char* __restrict__ rbs)
{
  __shared__ float wl[128];
  int t=threadIdx.x;
  if (t<128) wl[t]=wsk[t];
  __syncthreads();
  int slot = blockIdx.x*256+t;
  if (slot>=KP2) return;
  int n = slot2n(slot);
  if (n<0){ rfs[slot]=0.f; rbs[slot]=0; return; }
  int br = (slot>=8064);
  const float* wk = wl + br*64;
  float s = br ? ibs[0] : ubs[0];
  const float* qr = q + (size_t)n*64;
  #pragma unroll
  for (int d=0;d<64;d++) s += qr[d]*wk[d];
  unsigned char b = f2f8(expf(s));
  rbs[slot] = b;
  rfs[slot] = f8tof<0>((unsigned int)b);
}

// ---------------- K3: ONE pass over H, 128x128 tiles: W8, W8t (128B segments), Z, S2 ----------------
__global__ __launch_bounds__(256) void k_buildW(
    const int* __restrict__ H, const float* __restrict__ rfs, const unsigned char* __restrict__ rbs,
    unsigned char* __restrict__ W8, unsigned char* __restrict__ W8t,
    float* __restrict__ Zu, float* __restrict__ Zi,
    float* __restrict__ S2u, float* __restrict__ S2i)
{
  __shared__ unsigned char Tb[128*136];
  __shared__ float rl[128];
  __shared__ unsigned char rb[128];
  __shared__ float zp[8][128];
  __shared__ float sp[8][128];
  int t = threadIdx.x;
  int s0 = blockIdx.x*128;
  int g0 = blockIdx.y*128;
  int isItem = (s0 >= 8064);
  if (t < 128){
    int n = slot2n(s0+t);
    rl[t] = (n>=0) ? rfs[s0+t] : 0.f;
    rb[t] = (n>=0) ? rbs[s0+t] : (unsigned char)0;
  }
  __syncthreads();
  int rgrp = t>>5;
  int gq   = (t&31)*4;
  int cc   = gq>>4;
  int gi4  = gq&15;
  float za[4]={0.f,0.f,0.f,0.f}, sa[4]={0.f,0.f,0.f,0.f};
  #pragma unroll
  for (int i=0;i<16;i++){
    int row = i*8 + rgrp;
    int n = slot2n(s0+row);
    uchar4 pk; pk.x=0; pk.y=0; pk.z=0; pk.w=0;
    if (n >= 0){
      int4 hv = *(const int4*)(H + (size_t)n*G + g0 + gq);
      unsigned char rbv = rb[row];
      float rq = rl[row];
      if (hv.x){ pk.x=rbv; za[0]+=rq; sa[0]+=rq*rq; }
      if (hv.y){ pk.y=rbv; za[1]+=rq; sa[1]+=rq*rq; }
      if (hv.z){ pk.z=rbv; za[2]+=rq; sa[2]+=rq*rq; }
      if (hv.w){ pk.w=rbv; za[3]+=rq; sa[3]+=rq*rq; }
    }
    int scc = cc ^ ((row>>3)&7);
    *(uchar4*)(Tb + row*136 + (scc<<4) + gi4) = pk;
  }
  #pragma unroll
  for (int e=0;e<4;e++){ zp[rgrp][gq+e]=za[e]; sp[rgrp][gq+e]=sa[e]; }
  __syncthreads();
  #pragma unroll
  for (int p=0;p<4;p++){
    int row = p*32 + (t>>3);
    int c   = t&7;
    int scc = c ^ ((row>>3)&7);
    uint4 v = *(const uint4*)(Tb + row*136 + (scc<<4));
    *(uint4*)(W8t + (size_t)(s0+row)*G + g0 + (c<<4)) = v;
  }
  #pragma unroll
  for (int p=0;p<4;p++){
    int gl = p*32 + (t>>3);
    int sc = (t&7)*16;
    int gcc = gl>>4, gb = gl&15;
    __align__(16) unsigned char buf[16];
    #pragma unroll
    for (int j=0;j<16;j++){
      int row = sc+j;
      int scc = gcc ^ ((row>>3)&7);
      buf[j] = Tb[row*136 + (scc<<4) + gb];
    }
    *(uint4*)(W8 + (size_t)(g0+gl)*KP2 + s0 + sc) = *(uint4*)buf;
  }
  if (t < 128){
    float z=0.f, s2=0.f;
    #pragma unroll
    for (int j=0;j<8;j++){ z += zp[j][t]; s2 += sp[j][t]; }
    if (isItem){ atomicAdd(&Zi[g0+t], z); atomicAdd(&S2i[g0+t], s2); }
    else       { atomicAdd(&Zu[g0+t], z); atomicAdd(&S2u[g0+t], s2); }
  }
}

// ---------------- K4 (fused): block 0 = scales + (never-taken) patch; blocks 1.. = vt8 build ----------------
// vt8 region is pre-zeroed by the consolidated memset, so only the data half is written.
__global__ __launch_bounds__(256) void k_mid(
    const float* __restrict__ Zu, const float* __restrict__ Zi,
    const float* __restrict__ S2u, const float* __restrict__ S2i,
    float* __restrict__ Cu, float* __restrict__ Ci,
    float* __restrict__ cnu, float* __restrict__ cni, float* __restrict__ ninv,
    unsigned char* __restrict__ W8, unsigned char* __restrict__ W8t,
    const unsigned short* __restrict__ vrow, unsigned char* __restrict__ vt8)
{
  __shared__ unsigned short tile[64][65];
  int b = blockIdx.x;
  int t = threadIdx.x;
  if (b == 0){
    for (int g=t; g<G; g+=256){
      float zu=Zu[g], zi=Zi[g];
      int fu = !(zu>0.f), fi = !(zi>0.f);
      float cu = fu ? (1.f/(float)NU) : 1.f/zu;
      float ci = fi ? (1.f/(float)NI) : 1.f/zi;
      float nu  = fu ? (1.f/(float)NU) : S2u[g]*cu*cu;
      float ni_ = fi ? (1.f/(float)NI) : S2i[g]*ci*ci;
      float nv = rsqrtf(nu+ni_);
      Cu[g]=cu; Ci[g]=ci; ninv[g]=nv; cnu[g]=cu*nv; cni[g]=ci*nv;
      if (fu){ for (int k=0;k<NU;k++){ W8[(size_t)g*KP2+k]=0x38; W8t[(size_t)k*G+g]=0x38; } }
      if (fi){ for (int k=0;k<NI;k++){ W8[(size_t)g*KP2+8064+k]=0x38; W8t[(size_t)(8064+k)*G+g]=0x38; } }
    }
    return;
  }
  int s0 = (b-1)*64;
  int tc = t&63, tr = t>>6;
  #pragma unroll
  for (int i=0;i<16;i++){
    int row = tr+i*4;
    int n = slot2n(s0+row);
    tile[row][tc] = (n>=0) ? vrow[(size_t)n*64+tc] : (unsigned short)0;
  }
  __syncthreads();
  int dOff = (s0 >= 8064) ? 64 : 0;
  #pragma unroll
  for (int i=0;i<16;i++){
    int dd = tr+i*4;
    float v = bfu(tile[tc][dd]) * 16.f;
    vt8[(size_t)(dOff+dd)*KP2 + s0+tc] = f2f8(v);
  }
}

// ---------------- K6: fp8 GEMM C = A.B^T (k-contig byte rows), 128-elem k-tiles ----------------
// MODE 0: gf = (C_b/16) * (W8 . vt8^T), atomic f32, grid (32,1,16)
// MODE 1: tmpT8 = gfsT2_8 . W8t^T, fp8 out, A-half by J, grid (1,142,1)
// MODE 2: msg = (cn_b/64)*(W8 . tmpT8^T) atomic; deg = cn_b*(W8 . u8) fused, grid (32,1,16)
template<int MODE>
__global__ __launch_bounds__(256) void k_gemm(
    const unsigned char* __restrict__ A, const unsigned char* __restrict__ B,
    float* __restrict__ Cf, unsigned char* __restrict__ C8,
    const float* __restrict__ sU, const float* __restrict__ sI,
    const unsigned char* __restrict__ u8, float* __restrict__ deg,
    long ldA, long ldB, long ldc)
{
  __shared__ __align__(16) unsigned char As[128*128];
  __shared__ __align__(16) unsigned char Bs[128*128];
  int t=threadIdx.x, wave=t>>6, lane=t&63;
  int I=blockIdx.x, J=blockIdx.y, z=blockIdx.z;
  int kt0=0, ktn=0;
  const float* scale = nullptr;
  if (MODE==0){ kt0 = z*9; ktn = min(9, KT8-kt0); }
  else if (MODE==1){ kt0 = 0; ktn = 32; }
  else {
    if (z<8){ kt0 = z*8;             ktn = min(8,  UT8-kt0); scale = sU; }
    else    { kt0 = UT8 + (z-8)*10;  ktn = min(10, KT8-kt0); scale = sI; }
  }
  f32x4 acc[4][4];
  #pragma unroll
  for (int mi=0;mi<4;mi++)
    #pragma unroll
    for (int ni=0;ni<4;ni++){
      acc[mi][ni][0]=0.f; acc[mi][ni][1]=0.f; acc[mi][ni][2]=0.f; acc[mi][ni][3]=0.f;
    }
  f32x4 accd[4];
  if (MODE==2){
    #pragma unroll
    for (int mi=0;mi<4;mi++){ accd[mi][0]=0.f; accd[mi][1]=0.f; accd[mi][2]=0.f; accd[mi][3]=0.f; }
  }
  int l7 = lane&7, q4 = lane>>4, cl15 = lane&15;
  int rowOff = wave*8 + (lane>>3);
  int cchunk = (lane&7) ^ ((lane>>3)&7);
  long aRow0 = (MODE==1) ? ((J>=UT8)?128:0) : (long)I*128;
  const unsigned char* Abase = A + aRow0*ldA + (long)cchunk*16;
  const unsigned char* Bbase = B + (long)J*128*ldB + (long)cchunk*16;
  unsigned char* AsW = As + wave*1024;
  unsigned char* BsW = Bs + wave*1024;
  int mrow0 = (wave&1)*64, nrow0 = (wave>>1)*64;
  for (int kt=kt0; kt<kt0+ktn; ++kt){
    long k0 = (long)kt*128;
    #pragma unroll
    for (int rr=0; rr<4; rr++){
      async16(AsW + rr*4096, Abase + (long)(rr*32 + rowOff)*ldA + k0);
      async16(BsW + rr*4096, Bbase + (long)(rr*32 + rowOff)*ldB + k0);
    }
    __syncthreads();
    #pragma unroll
    for (int kk=0; kk<4; kk++){
      int xoff = (((kk*2 + (q4>>1)) ^ l7) << 4) + ((q4&1)<<3);
      long af[4], bf[4];
      #pragma unroll
      for (int mi=0;mi<4;mi++)
        af[mi] = *(const long*)(As + (mrow0 + mi*16 + cl15)*128 + xoff);
      #pragma unroll
      for (int ni=0;ni<4;ni++)
        bf[ni] = *(const long*)(Bs + (nrow0 + ni*16 + cl15)*128 + xoff);
      #pragma unroll
      for (int mi=0;mi<4;mi++)
        #pragma unroll
        for (int ni=0;ni<4;ni++)
          acc[mi][ni] = __builtin_amdgcn_mfma_f32_16x16x32_fp8_fp8(af[mi], bf[ni], acc[mi][ni], 0,0,0);
      if (MODE==2){
        long bu = 0;
        if (cl15==0) bu = *(const long*)(u8 + (size_t)kt*128 + kk*32 + q4*8);
        #pragma unroll
        for (int mi=0;mi<4;mi++)
          accd[mi] = __builtin_amdgcn_mfma_f32_16x16x32_fp8_fp8(af[mi], bu, accd[mi], 0,0,0);
      }
    }
    __syncthreads();
  }
  int cq = lane>>4, cl = lane&15;
  #pragma unroll
  for (int mi=0;mi<4;mi++)
    #pragma unroll
    for (int ni=0;ni<4;ni++)
      #pragma unroll
      for (int rg=0;rg<4;rg++){
        int gi = (MODE==1 ? 0 : I*128) + mrow0 + mi*16 + cq*4 + rg;
        int hi = J*128 + nrow0 + ni*16 + cl;
        float v = acc[mi][ni][rg];
        if (MODE==0){
          float sc = ((hi & 64) ? sI[gi] : sU[gi]) * 0.0625f;
          atomicAdd(&Cf[(size_t)gi*ldc + hi], v*sc);
        } else if (MODE==1){
          C8[(size_t)gi*ldc + hi] = f2f8(v);
        } else {
          atomicAdd(&Cf[(size_t)gi*ldc + hi], v*scale[gi]*0.015625f);
        }
      }
  if (MODE==2 && cl15==0){
    #pragma unroll
    for (int mi=0;mi<4;mi++)
      #pragma unroll
      for (int rg=0;rg<4;rg++){
        int gi = I*128 + mrow0 + mi*16 + cq*4 + rg;
        atomicAdd(&deg[gi], accd[mi][rg]*scale[gi]);
      }
  }
}

// ---------------- K7: gfsT2_8 (256 x G): rows d = fp8(gf*ninv*Cu*64), 128+d with Ci ----------------
__global__ __launch_bounds__(256) void k_buildGfsT2(const float* __restrict__ gf, const float* __restrict__ ninv,
    const float* __restrict__ Cu, const float* __restrict__ Ci, unsigned char* __restrict__ gfsT2_8){
  __shared__ float tile[64][65];
  int g0 = blockIdx.x*64, d0 = blockIdx.y*64;
  int tc=threadIdx.x&63, tr=threadIdx.x>>6;
  #pragma unroll
  for (int i=0;i<16;i++){
    int rr=tr+i*4;
    tile[rr][tc] = gf[(size_t)(g0+rr)*128 + d0+tc] * ninv[g0+rr];
  }
  __syncthreads();
  #pragma unroll
  for (int i=0;i<16;i++){
    int dd=tr+i*4;
    float v = tile[tc][dd] * 64.f;
    int g = g0+tc;
    gfsT2_8[(size_t)(d0+dd)*G + g]     = f2f8(v*Cu[g]);
    gfsT2_8[(size_t)(128+d0+dd)*G + g] = f2f8(v*Ci[g]);
  }
}

// ---------------- K8: u[k] = sum_g W8[g,k]*cn_b(k)[g] ----------------
__global__ __launch_bounds__(256) void k_u(const unsigned char* __restrict__ W8,
    const float* __restrict__ cnu, const float* __restrict__ cni, float* __restrict__ u){
  long k0 = ((long)blockIdx.x*256 + threadIdx.x)*8;
  if (k0 >= KP2) return;
  int g0 = blockIdx.y*64;
  const float* cn = (k0 < 8064) ? cnu : cni;
  float a[8];
  #pragma unroll
  for (int e=0;e<8;e++) a[e]=0.f;
  for (int j=0;j<64;j++){
    float c = cn[g0+j];
    long w = *(const long*)(W8 + (size_t)(g0+j)*KP2 + k0);
    unsigned int lo = (unsigned int)w, hi = (unsigned int)((unsigned long)w>>32);
    a[0] += f8tof<0>(lo)*c; a[1] += f8tof<1>(lo)*c; a[2] += f8tof<2>(lo)*c; a[3] += f8tof<3>(lo)*c;
    a[4] += f8tof<0>(hi)*c; a[5] += f8tof<1>(hi)*c; a[6] += f8tof<2>(hi)*c; a[7] += f8tof<3>(hi)*c;
  }
  #pragma unroll
  for (int e=0;e<8;e++) atomicAdd(&u[k0+e], a[e]);
}

// ---------------- K8b: u8 = fp8(u) ----------------
__global__ void k_u8(const float* __restrict__ u, unsigned char* __restrict__ u8){
  int k = blockIdx.x*256+threadIdx.x;
  if (k<KP2) u8[k] = f2f8(u[k]);
}

// ---------------- K9: out = sigmoid((0.8 gf + 0.2 msg/deg) @ gW^T + gb) ----------------
__global__ __launch_bounds__(256) void k_final(const float* __restrict__ gf, const float* __restrict__ msg,
    const float* __restrict__ deg, const float* __restrict__ gW, const float* __restrict__ gb,
    float* __restrict__ out)
{
  __shared__ float Wl[64*129];
  __shared__ float aggL[4][128];
  __shared__ float gbL[64];
  int t=threadIdx.x;
  for (int e=t; e<8192; e+=256){ int o=e>>7, dd=e&127; Wl[o*129+dd] = gW[e]; }
  if (t<64) gbL[t] = gb[t];
  int g0 = blockIdx.x*4;
  for (int e=t; e<512; e+=256){
    int gl=e>>7, dd=e&127; int g=g0+gl;
    float dv = deg[g];
    float hn = dv>0.f ? msg[(size_t)g*128+dd]/dv : 0.f;
    aggL[gl][dd] = 0.8f*gf[(size_t)g*128+dd] + 0.2f*hn;
  }
  __syncthreads();
  int gl = t>>6, o = t&63;
  float s = gbL[o];
  #pragma unroll
  for (int dd=0; dd<128; dd++) s += aggL[gl][dd]*Wl[o*129+dd];
  out[(size_t)(g0+gl)*64 + o] = 1.f/(1.f+expf(-s));
}

extern "C" void kernel_launch(void* const* d_in, const int* in_sizes, int n_in,
                              void* d_out, int out_size, void* d_ws, size_t ws_size,
                              hipStream_t stream)
{
  (void)in_sizes; (void)n_in; (void)out_size; (void)ws_size;
  const int* H = (const int*)d_in[0];
  const float* feats = (const float*)d_in[1];
  const float* uWq=(const float*)d_in[3];
  const float* ubq=(const float*)d_in[4];
  const float* uWk=(const float*)d_in[5];
  const float* ubk=(const float*)d_in[6];
  const float* uWv=(const float*)d_in[7];
  const float* ubv=(const float*)d_in[8];
  const float* uWs=(const float*)d_in[9];
  const float* ubs=(const float*)d_in[10];
  const float* iWq=(const float*)d_in[11];
  const float* ibq=(const float*)d_in[12];
  const float* iWk=(const float*)d_in[13];
  const float* ibk=(const float*)d_in[14];
  const float* iWv=(const float*)d_in[15];
  const float* ibv=(const float*)d_in[16];
  const float* iWs=(const float*)d_in[17];
  const float* ibs=(const float*)d_in[18];
  const float* gW =(const float*)d_in[19];
  const float* gb =(const float*)d_in[20];
  float* out = (float*)d_out;

  char* p = (char*)d_ws;
  auto alloc=[&](size_t b)->void*{ void* r=(void*)p; p += (b+255)&~(size_t)255; return r; };
  // --- zero region (single memset) ---
  char* zbase = p;
  float* wsk  = (float*)alloc(128*4);
  float* Zu   = (float*)alloc(G*4);
  float* Zi   = (float*)alloc(G*4);
  float* S2u  = (float*)alloc(G*4);
  float* S2i  = (float*)alloc(G*4);
  float* deg  = (float*)alloc(G*4);
  float* u    = (float*)alloc((size_t)KP2*4);
  float* gf   = (float*)alloc((size_t)G*128*4);
  float* msg  = (float*)alloc((size_t)G*128*4);
  unsigned char* vt8 = (unsigned char*)alloc((size_t)128*KP2);
  size_t zlen = (size_t)(p - zbase);
  // --- non-zeroed ---
  unsigned char* W8    = (unsigned char*)alloc((size_t)G*KP2);
  unsigned char* W8t   = (unsigned char*)alloc((size_t)KP2*G);
  unsigned char* tmpT8 = (unsigned char*)alloc((size_t)128*KP2);
  unsigned char* gfsT2_8=(unsigned char*)alloc((size_t)256*G);
  float* q    = (float*)alloc((size_t)NTOT*64*4);
  unsigned short* vrow=(unsigned short*)alloc((size_t)NTOT*64*2);
  float* rfs  = (float*)alloc((size_t)KP2*4);
  unsigned char* rbs = (unsigned char*)alloc((size_t)KP2);
  float* Cu   = (float*)alloc(G*4);
  float* Ci   = (float*)alloc(G*4);
  float* cnu  = (float*)alloc(G*4);
  float* cni  = (float*)alloc(G*4);
  float* ninv = (float*)alloc(G*4);
  unsigned char* u8 = (unsigned char*)alloc((size_t)KP2);

  (void)hipMemsetAsync(zbase, 0, zlen, stream);

  k_proj<<<128,256,0,stream>>>(feats, uWq,ubq,uWk,ubk,uWv,ubv,uWs,
                               iWq,ibq,iWk,ibk,iWv,ibv,iWs, q, vrow, wsk);
  k_score<<<(KP2+255)/256,256,0,stream>>>(q, wsk, ubs, ibs, rfs, rbs);
  k_buildW<<<dim3(NSL128,32),256,0,stream>>>(H, rfs, rbs, W8, W8t, Zu, Zi, S2u, S2i);
  // fused: scales + patch (block 0) and vt8 build (blocks 1..284)
  k_mid<<<NSL+1,256,0,stream>>>(Zu,Zi,S2u,S2i,Cu,Ci,cnu,cni,ninv,W8,W8t,vrow,vt8);
  // gf = (C_b/16) * (W8 . vt8^T)
  k_gemm<0><<<dim3(32,1,16),256,0,stream>>>(W8, vt8, gf, nullptr, Cu, Ci, nullptr, nullptr,
                                            (long)KP2, (long)KP2, 128);
  k_buildGfsT2<<<dim3(64,2),256,0,stream>>>(gf, ninv, Cu, Ci, gfsT2_8);
  // tmpT8[d][n] = fp8( sum_g gfsT2_8[d_half,g] * W8t[n,g] )
  k_gemm<1><<<dim3(1,KT8,1),256,0,stream>>>(gfsT2_8, W8t, nullptr, tmpT8, nullptr, nullptr, nullptr, nullptr,
                                            (long)G, (long)G, (long)KP2);
  // u = W8^T cn
  k_u<<<dim3(9,64),256,0,stream>>>(W8, cnu, cni, u);
  k_u8<<<(KP2+255)/256,256,0,stream>>>(u, u8);
  // msg = (cn_b/64) * (W8_b . tmpT8^T), deg fused
  k_gemm<2><<<dim3(32,1,16),256,0,stream>>>(W8, tmpT8, msg, nullptr, cnu, cni, u8, deg,
                                            (long)KP2, (long)KP2, 128);
  k_final<<<G/4,256,0,stream>>>(gf, msg, deg, gW, gb, out);
}

// Round 10
// 771.521 us; speedup vs baseline: 1.0579x; 1.0579x over previous
//
#include <hip/hip_runtime.h>
#include <hip/hip_bf16.h>
#include <cstdint>
#include <cstddef>

#define NU   8000
#define NI   10000
#define NTOT 18000
#define G    4096
#define KP2  18176      // slots: users 0..8063, items 8064..18175
#define NSL  284        // 64-slot tiles
#define NSL128 142      // 128-slot tiles
#define KT8  142        // 128-byte k-tiles
#define UT8  63         // user 128-tiles (63*128 = 8064)

typedef __attribute__((ext_vector_type(4))) float f32x4;

__device__ __forceinline__ float bfu(unsigned short u){
  return __uint_as_float(((unsigned)u)<<16);
}
__device__ __forceinline__ unsigned short f2b(float f){
  __hip_bfloat16 h = __float2bfloat16(f);
  return __builtin_bit_cast(unsigned short, h);
}
__device__ __forceinline__ unsigned char f2f8(float v){
  int p = __builtin_amdgcn_cvt_pk_fp8_f32(v, 0.f, 0, false);
  return (unsigned char)(p & 0xff);
}
template<int SEL>
__device__ __forceinline__ float f8tof(unsigned int w){
  return __builtin_amdgcn_cvt_f32_fp8((int)w, SEL);
}
__device__ __forceinline__ void async16(void* lds, const void* g){
  __builtin_amdgcn_global_load_lds((const __attribute__((address_space(1))) unsigned int*)g,
                                   (__attribute__((address_space(3))) unsigned int*)lds, 16, 0, 0);
}
__device__ __forceinline__ int slot2n(int s){
  return (s < 8064) ? (s < 8000 ? s : -1) : (s-64 < NTOT ? s-64 : -1);
}

// ---------------- K1: q/k/v projections, v rows, wsk = Ws @ k ----------------
__global__ __launch_bounds__(256) void k_proj(
    const float* __restrict__ feats,
    const float* uWq, const float* ubq, const float* uWk, const float* ubk,
    const float* uWv, const float* ubv, const float* uWs,
    const float* iWq, const float* ibq, const float* iWk, const float* ibk,
    const float* iWv, const float* ibv, const float* iWs,
    float* __restrict__ q, unsigned short* __restrict__ vrow, float* __restrict__ wsk)
{
  __shared__ unsigned short Wt[6*4096];
  __shared__ float bl[6*64];
  __shared__ float wacc[128];
  const float* mats[6]  = {uWq,uWk,uWv,iWq,iWk,iWv};
  const float* bias6[6] = {ubq,ubk,ubv,ibq,ibk,ibv};
  int t = threadIdx.x;
  for (int m=0;m<6;m++)
    for (int e=t; e<4096; e+=256){
      int dd = e>>6, jj = e&63;
      Wt[m*4096 + jj*64 + dd] = f2b(mats[m][e]);
    }
  for (int e=t; e<384; e+=256) bl[e] = bias6[e>>6][e&63];
  if (t<128) wacc[t]=0.f;
  __syncthreads();
  int wave=t>>6, lane=t&63;
  int gw = blockIdx.x*4+wave, nw = gridDim.x*4;
  float accU=0.f, accI=0.f;
  for (int n=gw; n<NTOT; n+=nw){
    int br = (n>=NU);
    const unsigned short* W = Wt + br*3*4096;
    const float* bb = bl + br*192;
    float x = feats[(size_t)n*64+lane];
    float qd=bb[lane], kd=bb[64+lane], vd=bb[128+lane];
    #pragma unroll 16
    for (int j=0;j<64;j++){
      float xj = __shfl(x, j, 64);
      qd += xj * bfu(W[       j*64+lane]);
      kd += xj * bfu(W[4096 + j*64+lane]);
      vd += xj * bfu(W[8192 + j*64+lane]);
    }
    q[(size_t)n*64+lane] = qd;
    vrow[(size_t)n*64+lane] = f2b(vd);
    float wsn = br ? iWs[n-NU] : uWs[n];
    if (br) accI += wsn*kd; else accU += wsn*kd;
  }
  atomicAdd(&wacc[lane], accU);
  atomicAdd(&wacc[64+lane], accI);
  __syncthreads();
  if (t<128) atomicAdd(&wsk[t], wacc[t]);
}

// ---------------- K2: per-slot r quantized to fp8; rfs = dequant, rbs = byte ----------------
__global__ __launch_bounds__(256) void k_score(const float* __restrict__ q, const float* __restrict__ wsk,
    const float* ubs, const float* ibs, float* __restrict__ rfs, unsigned char* __restrict__ rbs)
{
  __shared__ float wl[128];
  int t=threadIdx.x;
  if (t<128) wl[t]=wsk[t];
  __syncthreads();
  int slot = blockIdx.x*256+t;
  if (slot>=KP2) return;
  int n = slot2n(slot);
  if (n<0){ rfs[slot]=0.f; rbs[slot]=0; return; }
  int br = (slot>=8064);
  const float* wk = wl + br*64;
  float s = br ? ibs[0] : ubs[0];
  const float* qr = q + (size_t)n*64;
  #pragma unroll
  for (int d=0;d<64;d++) s += qr[d]*wk[d];
  unsigned char b = f2f8(expf(s));
  rbs[slot] = b;
  rfs[slot] = f8tof<0>((unsigned int)b);
}

// ---------------- K3: ONE pass over H, 128x128 tiles: W8, W8t (128B segments), Z, S2 ----------------
__global__ __launch_bounds__(256) void k_buildW(
    const int* __restrict__ H, const float* __restrict__ rfs, const unsigned char* __restrict__ rbs,
    unsigned char* __restrict__ W8, unsigned char* __restrict__ W8t,
    float* __restrict__ Zu, float* __restrict__ Zi,
    float* __restrict__ S2u, float* __restrict__ S2i)
{
  __shared__ unsigned char Tb[128*136];
  __shared__ float rl[128];
  __shared__ unsigned char rb[128];
  __shared__ float zp[8][128];
  __shared__ float sp[8][128];
  int t = threadIdx.x;
  int s0 = blockIdx.x*128;
  int g0 = blockIdx.y*128;
  int isItem = (s0 >= 8064);
  if (t < 128){
    int n = slot2n(s0+t);
    rl[t] = (n>=0) ? rfs[s0+t] : 0.f;
    rb[t] = (n>=0) ? rbs[s0+t] : (unsigned char)0;
  }
  __syncthreads();
  int rgrp = t>>5;
  int gq   = (t&31)*4;
  int cc   = gq>>4;
  int gi4  = gq&15;
  float za[4]={0.f,0.f,0.f,0.f}, sa[4]={0.f,0.f,0.f,0.f};
  #pragma unroll
  for (int i=0;i<16;i++){
    int row = i*8 + rgrp;
    int n = slot2n(s0+row);
    uchar4 pk; pk.x=0; pk.y=0; pk.z=0; pk.w=0;
    if (n >= 0){
      int4 hv = *(const int4*)(H + (size_t)n*G + g0 + gq);
      unsigned char rbv = rb[row];
      float rq = rl[row];
      if (hv.x){ pk.x=rbv; za[0]+=rq; sa[0]+=rq*rq; }
      if (hv.y){ pk.y=rbv; za[1]+=rq; sa[1]+=rq*rq; }
      if (hv.z){ pk.z=rbv; za[2]+=rq; sa[2]+=rq*rq; }
      if (hv.w){ pk.w=rbv; za[3]+=rq; sa[3]+=rq*rq; }
    }
    int scc = cc ^ ((row>>3)&7);
    *(uchar4*)(Tb + row*136 + (scc<<4) + gi4) = pk;
  }
  #pragma unroll
  for (int e=0;e<4;e++){ zp[rgrp][gq+e]=za[e]; sp[rgrp][gq+e]=sa[e]; }
  __syncthreads();
  #pragma unroll
  for (int p=0;p<4;p++){
    int row = p*32 + (t>>3);
    int c   = t&7;
    int scc = c ^ ((row>>3)&7);
    uint4 v = *(const uint4*)(Tb + row*136 + (scc<<4));
    *(uint4*)(W8t + (size_t)(s0+row)*G + g0 + (c<<4)) = v;
  }
  #pragma unroll
  for (int p=0;p<4;p++){
    int gl = p*32 + (t>>3);
    int sc = (t&7)*16;
    int gcc = gl>>4, gb = gl&15;
    __align__(16) unsigned char buf[16];
    #pragma unroll
    for (int j=0;j<16;j++){
      int row = sc+j;
      int scc = gcc ^ ((row>>3)&7);
      buf[j] = Tb[row*136 + (scc<<4) + gb];
    }
    *(uint4*)(W8 + (size_t)(g0+gl)*KP2 + s0 + sc) = *(uint4*)buf;
  }
  if (t < 128){
    float z=0.f, s2=0.f;
    #pragma unroll
    for (int j=0;j<8;j++){ z += zp[j][t]; s2 += sp[j][t]; }
    if (isItem){ atomicAdd(&Zi[g0+t], z); atomicAdd(&S2i[g0+t], s2); }
    else       { atomicAdd(&Zu[g0+t], z); atomicAdd(&S2u[g0+t], s2); }
  }
}

// ---------------- K4 (fused): block 0 = scales + (never-taken) patch; blocks 1.. = vt8 build ----------------
__global__ __launch_bounds__(256) void k_mid(
    const float* __restrict__ Zu, const float* __restrict__ Zi,
    const float* __restrict__ S2u, const float* __restrict__ S2i,
    float* __restrict__ Cu, float* __restrict__ Ci,
    float* __restrict__ cnu, float* __restrict__ cni, float* __restrict__ ninv,
    unsigned char* __restrict__ W8, unsigned char* __restrict__ W8t,
    const unsigned short* __restrict__ vrow, unsigned char* __restrict__ vt8)
{
  __shared__ unsigned short tile[64][65];
  int b = blockIdx.x;
  int t = threadIdx.x;
  if (b == 0){
    for (int g=t; g<G; g+=256){
      float zu=Zu[g], zi=Zi[g];
      int fu = !(zu>0.f), fi = !(zi>0.f);
      float cu = fu ? (1.f/(float)NU) : 1.f/zu;
      float ci = fi ? (1.f/(float)NI) : 1.f/zi;
      float nu  = fu ? (1.f/(float)NU) : S2u[g]*cu*cu;
      float ni_ = fi ? (1.f/(float)NI) : S2i[g]*ci*ci;
      float nv = rsqrtf(nu+ni_);
      Cu[g]=cu; Ci[g]=ci; ninv[g]=nv; cnu[g]=cu*nv; cni[g]=ci*nv;
      if (fu){ for (int k=0;k<NU;k++){ W8[(size_t)g*KP2+k]=0x38; W8t[(size_t)k*G+g]=0x38; } }
      if (fi){ for (int k=0;k<NI;k++){ W8[(size_t)g*KP2+8064+k]=0x38; W8t[(size_t)(8064+k)*G+g]=0x38; } }
    }
    return;
  }
  int s0 = (b-1)*64;
  int tc = t&63, tr = t>>6;
  #pragma unroll
  for (int i=0;i<16;i++){
    int row = tr+i*4;
    int n = slot2n(s0+row);
    tile[row][tc] = (n>=0) ? vrow[(size_t)n*64+tc] : (unsigned short)0;
  }
  __syncthreads();
  int dOff = (s0 >= 8064) ? 64 : 0;
  #pragma unroll
  for (int i=0;i<16;i++){
    int dd = tr+i*4;
    float v = bfu(tile[tc][dd]) * 16.f;
    vt8[(size_t)(dOff+dd)*KP2 + s0+tc] = f2f8(v);
  }
}

// ---------------- K6: fp8 GEMM C = A.B^T, atomic-free split-K to f32 slices ----------------
// MODE 0: gfsl[z] = W8 . vt8^T, grid (32,1,16)
// MODE 1: tmpsl[z] = gfsT2_8 . W8t^T (A-half by J), grid (1,142,4)
// MODE 2: msgsl[z] = W8 . tmpT8^T ; degsl[z] = W8 . u8, grid (32,1,16)
template<int MODE>
__global__ __launch_bounds__(256) void k_gemm(
    const unsigned char* __restrict__ A, const unsigned char* __restrict__ B,
    float* __restrict__ Cs, float* __restrict__ degsl,
    const unsigned char* __restrict__ u8,
    long ldA, long ldB, long ldc)
{
  __shared__ __align__(16) unsigned char As[128*128];
  __shared__ __align__(16) unsigned char Bs[128*128];
  int t=threadIdx.x, wave=t>>6, lane=t&63;
  int I=blockIdx.x, J=blockIdx.y, z=blockIdx.z;
  int kt0=0, ktn=0;
  if (MODE==0){ kt0 = z*9; ktn = min(9, KT8-kt0); }
  else if (MODE==1){ kt0 = z*8; ktn = 8; }
  else {
    if (z<8){ kt0 = z*8;             ktn = min(8,  UT8-kt0); }
    else    { kt0 = UT8 + (z-8)*10;  ktn = min(10, KT8-kt0); }
  }
  f32x4 acc[4][4];
  #pragma unroll
  for (int mi=0;mi<4;mi++)
    #pragma unroll
    for (int ni=0;ni<4;ni++){
      acc[mi][ni][0]=0.f; acc[mi][ni][1]=0.f; acc[mi][ni][2]=0.f; acc[mi][ni][3]=0.f;
    }
  f32x4 accd[4];
  if (MODE==2){
    #pragma unroll
    for (int mi=0;mi<4;mi++){ accd[mi][0]=0.f; accd[mi][1]=0.f; accd[mi][2]=0.f; accd[mi][3]=0.f; }
  }
  int l7 = lane&7, q4 = lane>>4, cl15 = lane&15;
  int rowOff = wave*8 + (lane>>3);
  int cchunk = (lane&7) ^ ((lane>>3)&7);
  long aRow0 = (MODE==1) ? ((J>=UT8)?128:0) : (long)I*128;
  const unsigned char* Abase = A + aRow0*ldA + (long)cchunk*16;
  const unsigned char* Bbase = B + (long)J*128*ldB + (long)cchunk*16;
  unsigned char* AsW = As + wave*1024;
  unsigned char* BsW = Bs + wave*1024;
  int mrow0 = (wave&1)*64, nrow0 = (wave>>1)*64;
  for (int kt=kt0; kt<kt0+ktn; ++kt){
    long k0 = (long)kt*128;
    #pragma unroll
    for (int rr=0; rr<4; rr++){
      async16(AsW + rr*4096, Abase + (long)(rr*32 + rowOff)*ldA + k0);
      async16(BsW + rr*4096, Bbase + (long)(rr*32 + rowOff)*ldB + k0);
    }
    __syncthreads();
    #pragma unroll
    for (int kk=0; kk<4; kk++){
      int xoff = (((kk*2 + (q4>>1)) ^ l7) << 4) + ((q4&1)<<3);
      long af[4], bf[4];
      #pragma unroll
      for (int mi=0;mi<4;mi++)
        af[mi] = *(const long*)(As + (mrow0 + mi*16 + cl15)*128 + xoff);
      #pragma unroll
      for (int ni=0;ni<4;ni++)
        bf[ni] = *(const long*)(Bs + (nrow0 + ni*16 + cl15)*128 + xoff);
      #pragma unroll
      for (int mi=0;mi<4;mi++)
        #pragma unroll
        for (int ni=0;ni<4;ni++)
          acc[mi][ni] = __builtin_amdgcn_mfma_f32_16x16x32_fp8_fp8(af[mi], bf[ni], acc[mi][ni], 0,0,0);
      if (MODE==2){
        long bu = 0;
        if (cl15==0) bu = *(const long*)(u8 + (size_t)kt*128 + kk*32 + q4*8);
        #pragma unroll
        for (int mi=0;mi<4;mi++)
          accd[mi] = __builtin_amdgcn_mfma_f32_16x16x32_fp8_fp8(af[mi], bu, accd[mi], 0,0,0);
      }
    }
    __syncthreads();
  }
  int cq = lane>>4, cl = lane&15;
  float* slice = (MODE==1) ? (Cs + (size_t)z*128*KP2) : (Cs + (size_t)z*G*128);
  #pragma unroll
  for (int mi=0;mi<4;mi++)
    #pragma unroll
    for (int ni=0;ni<4;ni++)
      #pragma unroll
      for (int rg=0;rg<4;rg++){
        int gi = (MODE==1 ? 0 : I*128) + mrow0 + mi*16 + cq*4 + rg;
        int hi = J*128 + nrow0 + ni*16 + cl;
        slice[(size_t)gi*ldc + hi] = acc[mi][ni][rg];
      }
  if (MODE==2 && (wave>>1)==0 && cl15==0){
    #pragma unroll
    for (int mi=0;mi<4;mi++)
      #pragma unroll
      for (int rg=0;rg<4;rg++){
        int gi = I*128 + mrow0 + mi*16 + cq*4 + rg;
        degsl[(size_t)z*G + gi] = accd[mi][rg];
      }
  }
}

// ---------------- R0: gf = (col-branch C / 16) * sum_z gfsl[z] ----------------
__global__ __launch_bounds__(256) void k_red0(const float* __restrict__ gfsl,
    const float* __restrict__ Cu, const float* __restrict__ Ci, float* __restrict__ gf){
  int idx = blockIdx.x*256 + threadIdx.x;       // 131072 float4 cells
  int gi = idx>>5;
  int hc = (idx&31)*4;
  size_t off = (size_t)gi*128 + hc;
  f32x4 s = {0.f,0.f,0.f,0.f};
  #pragma unroll
  for (int z=0;z<16;z++){
    f32x4 v = *(const f32x4*)(gfsl + (size_t)z*G*128 + off);
    s[0]+=v[0]; s[1]+=v[1]; s[2]+=v[2]; s[3]+=v[3];
  }
  float sc = ((hc&64) ? Ci[gi] : Cu[gi]) * 0.0625f;
  f32x4 r = {s[0]*sc, s[1]*sc, s[2]*sc, s[3]*sc};
  *(f32x4*)(gf + off) = r;
}

// ---------------- R1: tmpT8 = fp8( sum_z tmpsl[z] ) ----------------
__global__ __launch_bounds__(256) void k_red1(const float* __restrict__ tmpsl,
    unsigned char* __restrict__ tmpT8){
  int idx = blockIdx.x*256 + threadIdx.x;       // 581632 float4 cells
  int d = idx / 4544;
  int n = (idx - d*4544)*4;
  size_t off = (size_t)d*KP2 + n;
  f32x4 s = {0.f,0.f,0.f,0.f};
  #pragma unroll
  for (int z=0;z<4;z++){
    f32x4 v = *(const f32x4*)(tmpsl + (size_t)z*128*KP2 + off);
    s[0]+=v[0]; s[1]+=v[1]; s[2]+=v[2]; s[3]+=v[3];
  }
  uchar4 pk;
  pk.x = f2f8(s[0]); pk.y = f2f8(s[1]); pk.z = f2f8(s[2]); pk.w = f2f8(s[3]);
  *(uchar4*)(tmpT8 + off) = pk;
}

// ---------------- R2: msg = (cnu*sumU + cni*sumI)/64 ----------------
__global__ __launch_bounds__(256) void k_red2(const float* __restrict__ msgsl,
    const float* __restrict__ cnu, const float* __restrict__ cni, float* __restrict__ msg){
  int idx = blockIdx.x*256 + threadIdx.x;
  int gi = idx>>5;
  int hc = (idx&31)*4;
  size_t off = (size_t)gi*128 + hc;
  f32x4 su = {0.f,0.f,0.f,0.f}, si = {0.f,0.f,0.f,0.f};
  #pragma unroll
  for (int z=0;z<8;z++){
    f32x4 v = *(const f32x4*)(msgsl + (size_t)z*G*128 + off);
    su[0]+=v[0]; su[1]+=v[1]; su[2]+=v[2]; su[3]+=v[3];
  }
  #pragma unroll
  for (int z=8;z<16;z++){
    f32x4 v = *(const f32x4*)(msgsl + (size_t)z*G*128 + off);
    si[0]+=v[0]; si[1]+=v[1]; si[2]+=v[2]; si[3]+=v[3];
  }
  float a = cnu[gi]*0.015625f, b = cni[gi]*0.015625f;
  f32x4 r = {su[0]*a+si[0]*b, su[1]*a+si[1]*b, su[2]*a+si[2]*b, su[3]*a+si[3]*b};
  *(f32x4*)(msg + off) = r;
}

// ---------------- K7: gfsT2_8 (256 x G): rows d = fp8(gf*ninv*Cu*64), 128+d with Ci ----------------
__global__ __launch_bounds__(256) void k_buildGfsT2(const float* __restrict__ gf, const float* __restrict__ ninv,
    const float* __restrict__ Cu, const float* __restrict__ Ci, unsigned char* __restrict__ gfsT2_8){
  __shared__ float tile[64][65];
  int g0 = blockIdx.x*64, d0 = blockIdx.y*64;
  int tc=threadIdx.x&63, tr=threadIdx.x>>6;
  #pragma unroll
  for (int i=0;i<16;i++){
    int rr=tr+i*4;
    tile[rr][tc] = gf[(size_t)(g0+rr)*128 + d0+tc] * ninv[g0+rr];
  }
  __syncthreads();
  #pragma unroll
  for (int i=0;i<16;i++){
    int dd=tr+i*4;
    float v = tile[tc][dd] * 64.f;
    int g = g0+tc;
    gfsT2_8[(size_t)(d0+dd)*G + g]     = f2f8(v*Cu[g]);
    gfsT2_8[(size_t)(128+d0+dd)*G + g] = f2f8(v*Ci[g]);
  }
}

// ---------------- K8: u[k] = sum_g W8[g,k]*cn_b(k)[g] ----------------
__global__ __launch_bounds__(256) void k_u(const unsigned char* __restrict__ W8,
    const float* __restrict__ cnu, const float* __restrict__ cni, float* __restrict__ u){
  long k0 = ((long)blockIdx.x*256 + threadIdx.x)*8;
  if (k0 >= KP2) return;
  int g0 = blockIdx.y*512;
  const float* cn = (k0 < 8064) ? cnu : cni;
  float a[8];
  #pragma unroll
  for (int e=0;e<8;e++) a[e]=0.f;
  for (int j=0;j<512;j++){
    float c = cn[g0+j];
    long w = *(const long*)(W8 + (size_t)(g0+j)*KP2 + k0);
    unsigned int lo = (unsigned int)w, hi = (unsigned int)((unsigned long)w>>32);
    a[0] += f8tof<0>(lo)*c; a[1] += f8tof<1>(lo)*c; a[2] += f8tof<2>(lo)*c; a[3] += f8tof<3>(lo)*c;
    a[4] += f8tof<0>(hi)*c; a[5] += f8tof<1>(hi)*c; a[6] += f8tof<2>(hi)*c; a[7] += f8tof<3>(hi)*c;
  }
  #pragma unroll
  for (int e=0;e<8;e++) atomicAdd(&u[k0+e], a[e]);
}

// ---------------- K8b: u8 = fp8(u) ----------------
__global__ void k_u8(const float* __restrict__ u, unsigned char* __restrict__ u8){
  int k = blockIdx.x*256+threadIdx.x;
  if (k<KP2) u8[k] = f2f8(u[k]);
}

// ---------------- K9: deg from degsl; out = sigmoid((0.8 gf + 0.2 msg/deg) @ gW^T + gb) ----------------
__global__ __launch_bounds__(256) void k_final(const float* __restrict__ gf, const float* __restrict__ msg,
    const float* __restrict__ degsl, const float* __restrict__ cnu, const float* __restrict__ cni,
    const float* __restrict__ gW, const float* __restrict__ gb, float* __restrict__ out)
{
  __shared__ float Wl[64*129];
  __shared__ float aggL[4][128];
  __shared__ float gbL[64];
  __shared__ float degL[4];
  int t=threadIdx.x;
  for (int e=t; e<8192; e+=256){ int o=e>>7, dd=e&127; Wl[o*129+dd] = gW[e]; }
  if (t<64) gbL[t] = gb[t];
  int g0 = blockIdx.x*4;
  if (t<4){
    int g = g0+t;
    float su=0.f, si=0.f;
    #pragma unroll
    for (int z=0;z<8;z++)  su += degsl[(size_t)z*G + g];
    #pragma unroll
    for (int z=8;z<16;z++) si += degsl[(size_t)z*G + g];
    degL[t] = cnu[g]*su + cni[g]*si;
  }
  __syncthreads();
  for (int e=t; e<512; e+=256){
    int gl=e>>7, dd=e&127; int g=g0+gl;
    float dv = degL[gl];
    float hn = dv>0.f ? msg[(size_t)g*128+dd]/dv : 0.f;
    aggL[gl][dd] = 0.8f*gf[(size_t)g*128+dd] + 0.2f*hn;
  }
  __syncthreads();
  int gl = t>>6, o = t&63;
  float s = gbL[o];
  #pragma unroll
  for (int dd=0; dd<128; dd++) s += aggL[gl][dd]*Wl[o*129+dd];
  out[(size_t)(g0+gl)*64 + o] = 1.f/(1.f+expf(-s));
}

extern "C" void kernel_launch(void* const* d_in, const int* in_sizes, int n_in,
                              void* d_out, int out_size, void* d_ws, size_t ws_size,
                              hipStream_t stream)
{
  (void)in_sizes; (void)n_in; (void)out_size; (void)ws_size;
  const int* H = (const int*)d_in[0];
  const float* feats = (const float*)d_in[1];
  const float* uWq=(const float*)d_in[3];
  const float* ubq=(const float*)d_in[4];
  const float* uWk=(const float*)d_in[5];
  const float* ubk=(const float*)d_in[6];
  const float* uWv=(const float*)d_in[7];
  const float* ubv=(const float*)d_in[8];
  const float* uWs=(const float*)d_in[9];
  const float* ubs=(const float*)d_in[10];
  const float* iWq=(const float*)d_in[11];
  const float* ibq=(const float*)d_in[12];
  const float* iWk=(const float*)d_in[13];
  const float* ibk=(const float*)d_in[14];
  const float* iWv=(const float*)d_in[15];
  const float* ibv=(const float*)d_in[16];
  const float* iWs=(const float*)d_in[17];
  const float* ibs=(const float*)d_in[18];
  const float* gW =(const float*)d_in[19];
  const float* gb =(const float*)d_in[20];
  float* out = (float*)d_out;

  char* p = (char*)d_ws;
  auto alloc=[&](size_t b)->void*{ void* r=(void*)p; p += (b+255)&~(size_t)255; return r; };
  // --- zero region (single small memset) ---
  char* zbase = p;
  float* wsk  = (float*)alloc(128*4);
  float* Zu   = (float*)alloc(G*4);
  float* Zi   = (float*)alloc(G*4);
  float* S2u  = (float*)alloc(G*4);
  float* S2i  = (float*)alloc(G*4);
  float* u    = (float*)alloc((size_t)KP2*4);
  unsigned char* vt8 = (unsigned char*)alloc((size_t)128*KP2);
  size_t zlen = (size_t)(p - zbase);
  // --- non-zeroed ---
  unsigned char* W8    = (unsigned char*)alloc((size_t)G*KP2);
  unsigned char* W8t   = (unsigned char*)alloc((size_t)KP2*G);
  unsigned char* tmpT8 = (unsigned char*)alloc((size_t)128*KP2);
  unsigned char* gfsT2_8=(unsigned char*)alloc((size_t)256*G);
  float* gfsl = (float*)alloc((size_t)16*G*128*4);
  float* msgsl= (float*)alloc((size_t)16*G*128*4);
  float* tmpsl= (float*)alloc((size_t)4*128*KP2*4);
  float* degsl= (float*)alloc((size_t)16*G*4);
  float* gf   = (float*)alloc((size_t)G*128*4);
  float* msg  = (float*)alloc((size_t)G*128*4);
  float* q    = (float*)alloc((size_t)NTOT*64*4);
  unsigned short* vrow=(unsigned short*)alloc((size_t)NTOT*64*2);
  float* rfs  = (float*)alloc((size_t)KP2*4);
  unsigned char* rbs = (unsigned char*)alloc((size_t)KP2);
  float* Cu   = (float*)alloc(G*4);
  float* Ci   = (float*)alloc(G*4);
  float* cnu  = (float*)alloc(G*4);
  float* cni  = (float*)alloc(G*4);
  float* ninv = (float*)alloc(G*4);
  unsigned char* u8 = (unsigned char*)alloc((size_t)KP2);

  (void)hipMemsetAsync(zbase, 0, zlen, stream);

  k_proj<<<128,256,0,stream>>>(feats, uWq,ubq,uWk,ubk,uWv,ubv,uWs,
                               iWq,ibq,iWk,ibk,iWv,ibv,iWs, q, vrow, wsk);
  k_score<<<(KP2+255)/256,256,0,stream>>>(q, wsk, ubs, ibs, rfs, rbs);
  k_buildW<<<dim3(NSL128,32),256,0,stream>>>(H, rfs, rbs, W8, W8t, Zu, Zi, S2u, S2i);
  k_mid<<<NSL+1,256,0,stream>>>(Zu,Zi,S2u,S2i,Cu,Ci,cnu,cni,ninv,W8,W8t,vrow,vt8);
  // gf slices + reduce
  k_gemm<0><<<dim3(32,1,16),256,0,stream>>>(W8, vt8, gfsl, nullptr, nullptr,
                                            (long)KP2, (long)KP2, 128);
  k_red0<<<512,256,0,stream>>>(gfsl, Cu, Ci, gf);
  k_buildGfsT2<<<dim3(64,2),256,0,stream>>>(gf, ninv, Cu, Ci, gfsT2_8);
  // tmp slices + fp8 reduce
  k_gemm<1><<<dim3(1,KT8,4),256,0,stream>>>(gfsT2_8, W8t, tmpsl, nullptr, nullptr,
                                            (long)G, (long)G, (long)KP2);
  k_red1<<<2272,256,0,stream>>>(tmpsl, tmpT8);
  // u = W8^T cn
  k_u<<<dim3(9,8),256,0,stream>>>(W8, cnu, cni, u);
  k_u8<<<(KP2+255)/256,256,0,stream>>>(u, u8);
  // msg/deg slices + reduce
  k_gemm<2><<<dim3(32,1,16),256,0,stream>>>(W8, tmpT8, msgsl, degsl, u8,
                                            (long)KP2, (long)KP2, 128);
  k_red2<<<512,256,0,stream>>>(msgsl, cnu, cni, msg);
  k_final<<<G/4,256,0,stream>>>(gf, msg, degsl, cnu, cni, gW, gb, out);
}

// Round 11
// 745.085 us; speedup vs baseline: 1.0954x; 1.0355x over previous
//
#include <hip/hip_runtime.h>
#include <hip/hip_bf16.h>
#include <cstdint>
#include <cstddef>

#define NU   8000
#define NI   10000
#define NTOT 18000
#define G    4096
#define KP2  18176      // slots: users 0..8063, items 8064..18175
#define NSL  284        // 64-slot tiles
#define NSL128 142      // 128-slot tiles
#define KT8  142        // 128-byte k-tiles
#define UT8  63         // user 128-tiles (63*128 = 8064)

typedef __attribute__((ext_vector_type(4))) float f32x4;

__device__ __forceinline__ float bfu(unsigned short u){
  return __uint_as_float(((unsigned)u)<<16);
}
__device__ __forceinline__ unsigned short f2b(float f){
  __hip_bfloat16 h = __float2bfloat16(f);
  return __builtin_bit_cast(unsigned short, h);
}
__device__ __forceinline__ unsigned char f2f8(float v){
  int p = __builtin_amdgcn_cvt_pk_fp8_f32(v, 0.f, 0, false);
  return (unsigned char)(p & 0xff);
}
template<int SEL>
__device__ __forceinline__ float f8tof(unsigned int w){
  return __builtin_amdgcn_cvt_f32_fp8((int)w, SEL);
}
__device__ __forceinline__ void async16(void* lds, const void* g){
  __builtin_amdgcn_global_load_lds((const __attribute__((address_space(1))) unsigned int*)g,
                                   (__attribute__((address_space(3))) unsigned int*)lds, 16, 0, 0);
}
__device__ __forceinline__ int slot2n(int s){
  return (s < 8064) ? (s < 8000 ? s : -1) : (s-64 < NTOT ? s-64 : -1);
}

// ---------------- K1: q/k/v projections, v rows, wsk = Ws @ k ----------------
__global__ __launch_bounds__(256) void k_proj(
    const float* __restrict__ feats,
    const float* uWq, const float* ubq, const float* uWk, const float* ubk,
    const float* uWv, const float* ubv, const float* uWs,
    const float* iWq, const float* ibq, const float* iWk, const float* ibk,
    const float* iWv, const float* ibv, const float* iWs,
    float* __restrict__ q, unsigned short* __restrict__ vrow, float* __restrict__ wsk)
{
  __shared__ unsigned short Wt[6*4096];
  __shared__ float bl[6*64];
  __shared__ float wacc[128];
  const float* mats[6]  = {uWq,uWk,uWv,iWq,iWk,iWv};
  const float* bias6[6] = {ubq,ubk,ubv,ibq,ibk,ibv};
  int t = threadIdx.x;
  for (int m=0;m<6;m++)
    for (int e=t; e<4096; e+=256){
      int dd = e>>6, jj = e&63;
      Wt[m*4096 + jj*64 + dd] = f2b(mats[m][e]);
    }
  for (int e=t; e<384; e+=256) bl[e] = bias6[e>>6][e&63];
  if (t<128) wacc[t]=0.f;
  __syncthreads();
  int wave=t>>6, lane=t&63;
  int gw = blockIdx.x*4+wave, nw = gridDim.x*4;
  float accU=0.f, accI=0.f;
  for (int n=gw; n<NTOT; n+=nw){
    int br = (n>=NU);
    const unsigned short* W = Wt + br*3*4096;
    const float* bb = bl + br*192;
    float x = feats[(size_t)n*64+lane];
    float qd=bb[lane], kd=bb[64+lane], vd=bb[128+lane];
    #pragma unroll 16
    for (int j=0;j<64;j++){
      float xj = __shfl(x, j, 64);
      qd += xj * bfu(W[       j*64+lane]);
      kd += xj * bfu(W[4096 + j*64+lane]);
      vd += xj * bfu(W[8192 + j*64+lane]);
    }
    q[(size_t)n*64+lane] = qd;
    vrow[(size_t)n*64+lane] = f2b(vd);
    float wsn = br ? iWs[n-NU] : uWs[n];
    if (br) accI += wsn*kd; else accU += wsn*kd;
  }
  atomicAdd(&wacc[lane], accU);
  atomicAdd(&wacc[64+lane], accI);
  __syncthreads();
  if (t<128) atomicAdd(&wsk[t], wacc[t]);
}

// ---------------- K2: per-slot r quantized to fp8; rfs = dequant, rbs = byte ----------------
__global__ __launch_bounds__(256) void k_score(const float* __restrict__ q, const float* __restrict__ wsk,
    const float* ubs, const float* ibs, float* __restrict__ rfs, unsigned char* __restrict__ rbs)
{
  __shared__ float wl[128];
  int t=threadIdx.x;
  if (t<128) wl[t]=wsk[t];
  __syncthreads();
  int slot = blockIdx.x*256+t;
  if (slot>=KP2) return;
  int n = slot2n(slot);
  if (n<0){ rfs[slot]=0.f; rbs[slot]=0; return; }
  int br = (slot>=8064);
  const float* wk = wl + br*64;
  float s = br ? ibs[0] : ubs[0];
  const float* qr = q + (size_t)n*64;
  #pragma unroll
  for (int d=0;d<64;d++) s += qr[d]*wk[d];
  unsigned char b = f2f8(expf(s));
  rbs[slot] = b;
  rfs[slot] = f8tof<0>((unsigned int)b);
}

// ---------------- K3: ONE pass over H, 128x128 tiles: W8, W8t (128B segments), Z, S2 ----------------
__global__ __launch_bounds__(256) void k_buildW(
    const int* __restrict__ H, const float* __restrict__ rfs, const unsigned char* __restrict__ rbs,
    unsigned char* __restrict__ W8, unsigned char* __restrict__ W8t,
    float* __restrict__ Zu, float* __restrict__ Zi,
    float* __restrict__ S2u, float* __restrict__ S2i)
{
  __shared__ unsigned char Tb[128*136];
  __shared__ float rl[128];
  __shared__ unsigned char rb[128];
  __shared__ float zp[8][128];
  __shared__ float sp[8][128];
  int t = threadIdx.x;
  int s0 = blockIdx.x*128;
  int g0 = blockIdx.y*128;
  int isItem = (s0 >= 8064);
  if (t < 128){
    int n = slot2n(s0+t);
    rl[t] = (n>=0) ? rfs[s0+t] : 0.f;
    rb[t] = (n>=0) ? rbs[s0+t] : (unsigned char)0;
  }
  __syncthreads();
  int rgrp = t>>5;
  int gq   = (t&31)*4;
  int cc   = gq>>4;
  int gi4  = gq&15;
  float za[4]={0.f,0.f,0.f,0.f}, sa[4]={0.f,0.f,0.f,0.f};
  #pragma unroll
  for (int i=0;i<16;i++){
    int row = i*8 + rgrp;
    int n = slot2n(s0+row);
    uchar4 pk; pk.x=0; pk.y=0; pk.z=0; pk.w=0;
    if (n >= 0){
      int4 hv = *(const int4*)(H + (size_t)n*G + g0 + gq);
      unsigned char rbv = rb[row];
      float rq = rl[row];
      if (hv.x){ pk.x=rbv; za[0]+=rq; sa[0]+=rq*rq; }
      if (hv.y){ pk.y=rbv; za[1]+=rq; sa[1]+=rq*rq; }
      if (hv.z){ pk.z=rbv; za[2]+=rq; sa[2]+=rq*rq; }
      if (hv.w){ pk.w=rbv; za[3]+=rq; sa[3]+=rq*rq; }
    }
    int scc = cc ^ ((row>>3)&7);
    *(uchar4*)(Tb + row*136 + (scc<<4) + gi4) = pk;
  }
  #pragma unroll
  for (int e=0;e<4;e++){ zp[rgrp][gq+e]=za[e]; sp[rgrp][gq+e]=sa[e]; }
  __syncthreads();
  #pragma unroll
  for (int p=0;p<4;p++){
    int row = p*32 + (t>>3);
    int c   = t&7;
    int scc = c ^ ((row>>3)&7);
    uint4 v = *(const uint4*)(Tb + row*136 + (scc<<4));
    *(uint4*)(W8t + (size_t)(s0+row)*G + g0 + (c<<4)) = v;
  }
  #pragma unroll
  for (int p=0;p<4;p++){
    int gl = p*32 + (t>>3);
    int sc = (t&7)*16;
    int gcc = gl>>4, gb = gl&15;
    __align__(16) unsigned char buf[16];
    #pragma unroll
    for (int j=0;j<16;j++){
      int row = sc+j;
      int scc = gcc ^ ((row>>3)&7);
      buf[j] = Tb[row*136 + (scc<<4) + gb];
    }
    *(uint4*)(W8 + (size_t)(g0+gl)*KP2 + s0 + sc) = *(uint4*)buf;
  }
  if (t < 128){
    float z=0.f, s2=0.f;
    #pragma unroll
    for (int j=0;j<8;j++){ z += zp[j][t]; s2 += sp[j][t]; }
    if (isItem){ atomicAdd(&Zi[g0+t], z); atomicAdd(&S2i[g0+t], s2); }
    else       { atomicAdd(&Zu[g0+t], z); atomicAdd(&S2u[g0+t], s2); }
  }
}

// ---------------- K4 (fused): block 0 = scales (+cn8) + (never-taken) patch; blocks 1.. = vt8 ----------------
__global__ __launch_bounds__(256) void k_mid(
    const float* __restrict__ Zu, const float* __restrict__ Zi,
    const float* __restrict__ S2u, const float* __restrict__ S2i,
    float* __restrict__ Cu, float* __restrict__ Ci,
    float* __restrict__ cnu, float* __restrict__ cni, float* __restrict__ ninv,
    unsigned char* __restrict__ cn8u, unsigned char* __restrict__ cn8i,
    unsigned char* __restrict__ W8, unsigned char* __restrict__ W8t,
    const unsigned short* __restrict__ vrow, unsigned char* __restrict__ vt8)
{
  __shared__ unsigned short tile[64][65];
  int b = blockIdx.x;
  int t = threadIdx.x;
  if (b == 0){
    for (int g=t; g<G; g+=256){
      float zu=Zu[g], zi=Zi[g];
      int fu = !(zu>0.f), fi = !(zi>0.f);
      float cu = fu ? (1.f/(float)NU) : 1.f/zu;
      float ci = fi ? (1.f/(float)NI) : 1.f/zi;
      float nu  = fu ? (1.f/(float)NU) : S2u[g]*cu*cu;
      float ni_ = fi ? (1.f/(float)NI) : S2i[g]*ci*ci;
      float nv = rsqrtf(nu+ni_);
      Cu[g]=cu; Ci[g]=ci; ninv[g]=nv; cnu[g]=cu*nv; cni[g]=ci*nv;
      cn8u[g] = f2f8(cu*nv*64.f);
      cn8i[g] = f2f8(ci*nv*64.f);
      if (fu){ for (int k=0;k<NU;k++){ W8[(size_t)g*KP2+k]=0x38; W8t[(size_t)k*G+g]=0x38; } }
      if (fi){ for (int k=0;k<NI;k++){ W8[(size_t)g*KP2+8064+k]=0x38; W8t[(size_t)(8064+k)*G+g]=0x38; } }
    }
    return;
  }
  int s0 = (b-1)*64;
  int tc = t&63, tr = t>>6;
  #pragma unroll
  for (int i=0;i<16;i++){
    int row = tr+i*4;
    int n = slot2n(s0+row);
    tile[row][tc] = (n>=0) ? vrow[(size_t)n*64+tc] : (unsigned short)0;
  }
  __syncthreads();
  int dOff = (s0 >= 8064) ? 64 : 0;
  #pragma unroll
  for (int i=0;i<16;i++){
    int dd = tr+i*4;
    float v = bfu(tile[tc][dd]) * 16.f;
    vt8[(size_t)(dOff+dd)*KP2 + s0+tc] = f2f8(v);
  }
}

// ---------------- K6: fp8 GEMM C = A.B^T, atomic-free split-K to f32 slices ----------------
// MODE 0: gfsl[z] = W8 . vt8^T, grid (32,1,8)
// MODE 1: tmpsl[z] = gfsT2_8 . W8t^T (A-half by J) + fused u-row (cn8 . W8t^T), grid (1,142,2)
// MODE 2: msgsl[z] = W8 . tmpT8^T ; degsl[z] = W8 . u8, grid (32,1,8) branch-pure z
template<int MODE>
__global__ __launch_bounds__(256) void k_gemm(
    const unsigned char* __restrict__ A, const unsigned char* __restrict__ B,
    float* __restrict__ Cs, float* __restrict__ degsl,
    const unsigned char* __restrict__ u8,
    const unsigned char* __restrict__ cn8u, const unsigned char* __restrict__ cn8i,
    float* __restrict__ uslice,
    long ldA, long ldB, long ldc)
{
  __shared__ __align__(16) unsigned char As[128*128];
  __shared__ __align__(16) unsigned char Bs[128*128];
  int t=threadIdx.x, wave=t>>6, lane=t&63;
  int I=blockIdx.x, J=blockIdx.y, z=blockIdx.z;
  int kt0=0, ktn=0;
  if (MODE==0){ kt0 = z*18; ktn = min(18, KT8-kt0); }
  else if (MODE==1){ kt0 = z*16; ktn = 16; }
  else {
    if (z<4){ kt0 = z*16;            ktn = min(16, UT8-kt0); }
    else    { kt0 = UT8 + (z-4)*20;  ktn = min(20, KT8-kt0); }
  }
  f32x4 acc[4][4];
  #pragma unroll
  for (int mi=0;mi<4;mi++)
    #pragma unroll
    for (int ni=0;ni<4;ni++){
      acc[mi][ni][0]=0.f; acc[mi][ni][1]=0.f; acc[mi][ni][2]=0.f; acc[mi][ni][3]=0.f;
    }
  f32x4 accd[4];
  if (MODE==2){
    #pragma unroll
    for (int mi=0;mi<4;mi++){ accd[mi][0]=0.f; accd[mi][1]=0.f; accd[mi][2]=0.f; accd[mi][3]=0.f; }
  }
  f32x4 accu[4];
  if (MODE==1){
    #pragma unroll
    for (int ni=0;ni<4;ni++){ accu[ni][0]=0.f; accu[ni][1]=0.f; accu[ni][2]=0.f; accu[ni][3]=0.f; }
  }
  int l7 = lane&7, q4 = lane>>4, cl15 = lane&15;
  int rowOff = wave*8 + (lane>>3);
  int cchunk = (lane&7) ^ ((lane>>3)&7);
  long aRow0 = (MODE==1) ? ((J>=UT8)?128:0) : (long)I*128;
  const unsigned char* Abase = A + aRow0*ldA + (long)cchunk*16;
  const unsigned char* Bbase = B + (long)J*128*ldB + (long)cchunk*16;
  const unsigned char* cnrow = (MODE==1) ? ((J>=UT8) ? cn8i : cn8u) : nullptr;
  unsigned char* AsW = As + wave*1024;
  unsigned char* BsW = Bs + wave*1024;
  int mrow0 = (wave&1)*64, nrow0 = (wave>>1)*64;
  for (int kt=kt0; kt<kt0+ktn; ++kt){
    long k0 = (long)kt*128;
    #pragma unroll
    for (int rr=0; rr<4; rr++){
      async16(AsW + rr*4096, Abase + (long)(rr*32 + rowOff)*ldA + k0);
      async16(BsW + rr*4096, Bbase + (long)(rr*32 + rowOff)*ldB + k0);
    }
    __syncthreads();
    #pragma unroll
    for (int kk=0; kk<4; kk++){
      int xoff = (((kk*2 + (q4>>1)) ^ l7) << 4) + ((q4&1)<<3);
      long af[4], bf[4];
      #pragma unroll
      for (int mi=0;mi<4;mi++)
        af[mi] = *(const long*)(As + (mrow0 + mi*16 + cl15)*128 + xoff);
      #pragma unroll
      for (int ni=0;ni<4;ni++)
        bf[ni] = *(const long*)(Bs + (nrow0 + ni*16 + cl15)*128 + xoff);
      #pragma unroll
      for (int mi=0;mi<4;mi++)
        #pragma unroll
        for (int ni=0;ni<4;ni++)
          acc[mi][ni] = __builtin_amdgcn_mfma_f32_16x16x32_fp8_fp8(af[mi], bf[ni], acc[mi][ni], 0,0,0);
      if (MODE==2){
        long bu = 0;
        if (cl15==0) bu = *(const long*)(u8 + (size_t)kt*128 + kk*32 + q4*8);
        #pragma unroll
        for (int mi=0;mi<4;mi++)
          accd[mi] = __builtin_amdgcn_mfma_f32_16x16x32_fp8_fp8(af[mi], bu, accd[mi], 0,0,0);
      }
      if (MODE==1){
        long au = 0;
        if (cl15==0) au = *(const long*)(cnrow + (size_t)kt*128 + kk*32 + q4*8);
        #pragma unroll
        for (int ni=0;ni<4;ni++)
          accu[ni] = __builtin_amdgcn_mfma_f32_16x16x32_fp8_fp8(au, bf[ni], accu[ni], 0,0,0);
      }
    }
    __syncthreads();
  }
  int cq = lane>>4, cl = lane&15;
  float* slice = (MODE==1) ? (Cs + (size_t)z*128*KP2) : (Cs + (size_t)z*G*128);
  #pragma unroll
  for (int mi=0;mi<4;mi++)
    #pragma unroll
    for (int ni=0;ni<4;ni++)
      #pragma unroll
      for (int rg=0;rg<4;rg++){
        int gi = (MODE==1 ? 0 : I*128) + mrow0 + mi*16 + cq*4 + rg;
        int hi = J*128 + nrow0 + ni*16 + cl;
        slice[(size_t)gi*ldc + hi] = acc[mi][ni][rg];
      }
  if (MODE==2 && (wave>>1)==0 && cl15==0){
    #pragma unroll
    for (int mi=0;mi<4;mi++)
      #pragma unroll
      for (int rg=0;rg<4;rg++){
        int gi = I*128 + mrow0 + mi*16 + cq*4 + rg;
        degsl[(size_t)z*G + gi] = accd[mi][rg];
      }
  }
  if (MODE==1 && (wave&1)==0 && q4==0){
    #pragma unroll
    for (int ni=0;ni<4;ni++){
      int si = J*128 + nrow0 + ni*16 + cl15;
      uslice[(size_t)z*KP2 + si] = accu[ni][0];
    }
  }
}

// ---------------- GFPOST: gf = (C_d/16)*sum_z gfsl ; gfsT2_8 both halves (fused red0+buildGfsT2) ----------------
__global__ __launch_bounds__(256) void k_gfpost(const float* __restrict__ gfsl,
    const float* __restrict__ Cu, const float* __restrict__ Ci, const float* __restrict__ ninv,
    float* __restrict__ gf, unsigned char* __restrict__ gfsT2_8)
{
  __shared__ float tile[64][65];
  int g0 = blockIdx.x*64, d0 = blockIdx.y*64;
  int tc=threadIdx.x&63, tr=threadIdx.x>>6;
  const float* Cd = blockIdx.y ? Ci : Cu;     // gf columns 64..127 are item-d
  #pragma unroll
  for (int i=0;i<16;i++){
    int rr=tr+i*4;
    size_t off = (size_t)(g0+rr)*128 + d0+tc;
    float s = 0.f;
    #pragma unroll
    for (int zz=0;zz<8;zz++) s += gfsl[(size_t)zz*G*128 + off];
    float gfv = s * Cd[g0+rr] * 0.0625f;
    gf[off] = gfv;
    tile[rr][tc] = gfv * ninv[g0+rr];
  }
  __syncthreads();
  #pragma unroll
  for (int i=0;i<16;i++){
    int dd=tr+i*4;
    float v = tile[tc][dd] * 64.f;
    int g = g0+tc;
    gfsT2_8[(size_t)(d0+dd)*G + g]     = f2f8(v*Cu[g]);
    gfsT2_8[(size_t)(128+d0+dd)*G + g] = f2f8(v*Ci[g]);
  }
}

// ---------------- R1: tmpT8 = fp8(sum_z tmpsl) ; u8 = fp8(sum_z uslice / 64) ----------------
__global__ __launch_bounds__(256) void k_red1(const float* __restrict__ tmpsl,
    unsigned char* __restrict__ tmpT8, const float* __restrict__ uslice, unsigned char* __restrict__ u8){
  int b = blockIdx.x, t = threadIdx.x;
  if (b >= 2272){
    int idx2 = (b-2272)*256 + t;
    if (idx2 < KP2/4){
      size_t off = (size_t)idx2*4;
      f32x4 s = *(const f32x4*)(uslice + off);
      f32x4 s2 = *(const f32x4*)(uslice + (size_t)KP2 + off);
      uchar4 pk;
      pk.x = f2f8((s[0]+s2[0])*0.015625f);
      pk.y = f2f8((s[1]+s2[1])*0.015625f);
      pk.z = f2f8((s[2]+s2[2])*0.015625f);
      pk.w = f2f8((s[3]+s2[3])*0.015625f);
      *(uchar4*)(u8 + off) = pk;
    }
    return;
  }
  int idx = b*256 + t;
  int d = idx / 4544;
  int n = (idx - d*4544)*4;
  size_t off = (size_t)d*KP2 + n;
  f32x4 a = *(const f32x4*)(tmpsl + off);
  f32x4 c = *(const f32x4*)(tmpsl + (size_t)128*KP2 + off);
  uchar4 pk;
  pk.x = f2f8(a[0]+c[0]); pk.y = f2f8(a[1]+c[1]); pk.z = f2f8(a[2]+c[2]); pk.w = f2f8(a[3]+c[3]);
  *(uchar4*)(tmpT8 + off) = pk;
}

// ---------------- R2: msg = (cnu*sumU + cni*sumI)/64 ----------------
__global__ __launch_bounds__(256) void k_red2(const float* __restrict__ msgsl,
    const float* __restrict__ cnu, const float* __restrict__ cni, float* __restrict__ msg){
  int idx = blockIdx.x*256 + threadIdx.x;
  int gi = idx>>5;
  int hc = (idx&31)*4;
  size_t off = (size_t)gi*128 + hc;
  f32x4 su = {0.f,0.f,0.f,0.f}, si = {0.f,0.f,0.f,0.f};
  #pragma unroll
  for (int z=0;z<4;z++){
    f32x4 v = *(const f32x4*)(msgsl + (size_t)z*G*128 + off);
    su[0]+=v[0]; su[1]+=v[1]; su[2]+=v[2]; su[3]+=v[3];
  }
  #pragma unroll
  for (int z=4;z<8;z++){
    f32x4 v = *(const f32x4*)(msgsl + (size_t)z*G*128 + off);
    si[0]+=v[0]; si[1]+=v[1]; si[2]+=v[2]; si[3]+=v[3];
  }
  float a = cnu[gi]*0.015625f, b = cni[gi]*0.015625f;
  f32x4 r = {su[0]*a+si[0]*b, su[1]*a+si[1]*b, su[2]*a+si[2]*b, su[3]*a+si[3]*b};
  *(f32x4*)(msg + off) = r;
}

// ---------------- K9: deg from degsl; out = sigmoid((0.8 gf + 0.2 msg/deg) @ gW^T + gb) ----------------
__global__ __launch_bounds__(256) void k_final(const float* __restrict__ gf, const float* __restrict__ msg,
    const float* __restrict__ degsl, const float* __restrict__ cnu, const float* __restrict__ cni,
    const float* __restrict__ gW, const float* __restrict__ gb, float* __restrict__ out)
{
  __shared__ float Wl[64*129];
  __shared__ float aggL[4][128];
  __shared__ float gbL[64];
  __shared__ float degL[4];
  int t=threadIdx.x;
  for (int e=t; e<8192; e+=256){ int o=e>>7, dd=e&127; Wl[o*129+dd] = gW[e]; }
  if (t<64) gbL[t] = gb[t];
  int g0 = blockIdx.x*4;
  if (t<4){
    int g = g0+t;
    float su=0.f, si=0.f;
    #pragma unroll
    for (int z=0;z<4;z++) su += degsl[(size_t)z*G + g];
    #pragma unroll
    for (int z=4;z<8;z++) si += degsl[(size_t)z*G + g];
    degL[t] = cnu[g]*su + cni[g]*si;
  }
  __syncthreads();
  for (int e=t; e<512; e+=256){
    int gl=e>>7, dd=e&127; int g=g0+gl;
    float dv = degL[gl];
    float hn = dv>0.f ? msg[(size_t)g*128+dd]/dv : 0.f;
    aggL[gl][dd] = 0.8f*gf[(size_t)g*128+dd] + 0.2f*hn;
  }
  __syncthreads();
  int gl = t>>6, o = t&63;
  float s = gbL[o];
  #pragma unroll
  for (int dd=0; dd<128; dd++) s += aggL[gl][dd]*Wl[o*129+dd];
  out[(size_t)(g0+gl)*64 + o] = 1.f/(1.f+expf(-s));
}

extern "C" void kernel_launch(void* const* d_in, const int* in_sizes, int n_in,
                              void* d_out, int out_size, void* d_ws, size_t ws_size,
                              hipStream_t stream)
{
  (void)in_sizes; (void)n_in; (void)out_size; (void)ws_size;
  const int* H = (const int*)d_in[0];
  const float* feats = (const float*)d_in[1];
  const float* uWq=(const float*)d_in[3];
  const float* ubq=(const float*)d_in[4];
  const float* uWk=(const float*)d_in[5];
  const float* ubk=(const float*)d_in[6];
  const float* uWv=(const float*)d_in[7];
  const float* ubv=(const float*)d_in[8];
  const float* uWs=(const float*)d_in[9];
  const float* ubs=(const float*)d_in[10];
  const float* iWq=(const float*)d_in[11];
  const float* ibq=(const float*)d_in[12];
  const float* iWk=(const float*)d_in[13];
  const float* ibk=(const float*)d_in[14];
  const float* iWv=(const float*)d_in[15];
  const float* ibv=(const float*)d_in[16];
  const float* iWs=(const float*)d_in[17];
  const float* ibs=(const float*)d_in[18];
  const float* gW =(const float*)d_in[19];
  const float* gb =(const float*)d_in[20];
  float* out = (float*)d_out;

  char* p = (char*)d_ws;
  auto alloc=[&](size_t b)->void*{ void* r=(void*)p; p += (b+255)&~(size_t)255; return r; };
  // --- zero region (single small memset) ---
  char* zbase = p;
  float* wsk  = (float*)alloc(128*4);
  float* Zu   = (float*)alloc(G*4);
  float* Zi   = (float*)alloc(G*4);
  float* S2u  = (float*)alloc(G*4);
  float* S2i  = (float*)alloc(G*4);
  unsigned char* vt8 = (unsigned char*)alloc((size_t)128*KP2);
  size_t zlen = (size_t)(p - zbase);
  // --- non-zeroed ---
  unsigned char* W8    = (unsigned char*)alloc((size_t)G*KP2);
  unsigned char* W8t   = (unsigned char*)alloc((size_t)KP2*G);
  unsigned char* tmpT8 = (unsigned char*)alloc((size_t)128*KP2);
  unsigned char* gfsT2_8=(unsigned char*)alloc((size_t)256*G);
  float* gfsl = (float*)alloc((size_t)8*G*128*4);
  float* msgsl= (float*)alloc((size_t)8*G*128*4);
  float* tmpsl= (float*)alloc((size_t)2*128*KP2*4);
  float* uslice=(float*)alloc((size_t)2*KP2*4);
  float* degsl= (float*)alloc((size_t)8*G*4);
  float* gf   = (float*)alloc((size_t)G*128*4);
  float* msg  = (float*)alloc((size_t)G*128*4);
  float* q    = (float*)alloc((size_t)NTOT*64*4);
  unsigned short* vrow=(unsigned short*)alloc((size_t)NTOT*64*2);
  float* rfs  = (float*)alloc((size_t)KP2*4);
  unsigned char* rbs = (unsigned char*)alloc((size_t)KP2);
  float* Cu   = (float*)alloc(G*4);
  float* Ci   = (float*)alloc(G*4);
  float* cnu  = (float*)alloc(G*4);
  float* cni  = (float*)alloc(G*4);
  float* ninv = (float*)alloc(G*4);
  unsigned char* cn8u = (unsigned char*)alloc(G);
  unsigned char* cn8i = (unsigned char*)alloc(G);
  unsigned char* u8 = (unsigned char*)alloc((size_t)KP2);

  (void)hipMemsetAsync(zbase, 0, zlen, stream);

  k_proj<<<128,256,0,stream>>>(feats, uWq,ubq,uWk,ubk,uWv,ubv,uWs,
                               iWq,ibq,iWk,ibk,iWv,ibv,iWs, q, vrow, wsk);
  k_score<<<(KP2+255)/256,256,0,stream>>>(q, wsk, ubs, ibs, rfs, rbs);
  k_buildW<<<dim3(NSL128,32),256,0,stream>>>(H, rfs, rbs, W8, W8t, Zu, Zi, S2u, S2i);
  k_mid<<<NSL+1,256,0,stream>>>(Zu,Zi,S2u,S2i,Cu,Ci,cnu,cni,ninv,cn8u,cn8i,W8,W8t,vrow,vt8);
  // gf slices + fused reduce/transpose
  k_gemm<0><<<dim3(32,1,8),256,0,stream>>>(W8, vt8, gfsl, nullptr, nullptr, nullptr, nullptr, nullptr,
                                           (long)KP2, (long)KP2, 128);
  k_gfpost<<<dim3(64,2),256,0,stream>>>(gfsl, Cu, Ci, ninv, gf, gfsT2_8);
  // tmp slices (+ fused u-row) + fp8 reduce
  k_gemm<1><<<dim3(1,KT8,2),256,0,stream>>>(gfsT2_8, W8t, tmpsl, nullptr, nullptr, cn8u, cn8i, uslice,
                                            (long)G, (long)G, (long)KP2);
  k_red1<<<2272+18,256,0,stream>>>(tmpsl, tmpT8, uslice, u8);
  // msg/deg slices + reduce
  k_gemm<2><<<dim3(32,1,8),256,0,stream>>>(W8, tmpT8, msgsl, degsl, u8, nullptr, nullptr, nullptr,
                                           (long)KP2, (long)KP2, 128);
  k_red2<<<512,256,0,stream>>>(msgsl, cnu, cni, msg);
  k_final<<<G/4,256,0,stream>>>(gf, msg, degsl, cnu, cni, gW, gb, out);
}